// Round 6
// baseline (5006.779 us; speedup 1.0000x reference)
//
#include <hip/hip_runtime.h>
#include <hip/hip_bf16.h>

#define H     768
#define G3    2304
#define BATCH 16
#define TLEN  1024
#define DOUT  512
#define SLICE 32
#define WPG   24      // workgroups per group (768/32)
#define NWG   72      // 3 groups * 24
#define NTHR  384     // 6 waves

typedef __attribute__((ext_vector_type(8))) short short8;
typedef __attribute__((ext_vector_type(4))) float f32x4;
typedef __attribute__((ext_vector_type(4))) unsigned int u32x4;

union U8 { short8 s; unsigned u[4]; unsigned long long q[2]; };

__device__ __forceinline__ float b2f(ushort u) {
  union { unsigned int ui; float f; } v; v.ui = ((unsigned int)u) << 16; return v.f;
}
__device__ __forceinline__ ushort f2b(float f) {
  union { float f; unsigned int ui; } v; v.f = f;
  unsigned int u = v.ui;
  return (ushort)((u + 0x7fffu + ((u >> 16) & 1u)) >> 16);
}

// ---- agent-scope (cross-XCD coherent) relaxed accessors ----
__device__ __forceinline__ unsigned long long agent_ld64(const void* p) {
  return __hip_atomic_load((const unsigned long long*)p, __ATOMIC_RELAXED, __HIP_MEMORY_SCOPE_AGENT);
}
__device__ __forceinline__ unsigned agent_ld32(const void* p) {
  return __hip_atomic_load((const unsigned*)p, __ATOMIC_RELAXED, __HIP_MEMORY_SCOPE_AGENT);
}
__device__ __forceinline__ void agent_st32(void* p, unsigned v) {
  __hip_atomic_store((unsigned*)p, v, __ATOMIC_RELAXED, __HIP_MEMORY_SCOPE_AGENT);
}
__device__ __forceinline__ void agent_st64(void* p, unsigned long long v) {
  __hip_atomic_store((unsigned long long*)p, v, __ATOMIC_RELAXED, __HIP_MEMORY_SCOPE_AGENT);
}

// 64B coherent (agent-scope, L1-bypassing) load: 4 x dwordx4 with sc0 sc1.
__device__ __forceinline__ void ld64B_agent(const void* p, u32x4* r) {
  asm volatile(
    "global_load_dwordx4 %0, %4, off sc0 sc1\n\t"
    "global_load_dwordx4 %1, %4, off offset:16 sc0 sc1\n\t"
    "global_load_dwordx4 %2, %4, off offset:32 sc0 sc1\n\t"
    "global_load_dwordx4 %3, %4, off offset:48 sc0 sc1\n\t"
    "s_waitcnt vmcnt(0)"
    : "=&v"(r[0]), "=&v"(r[1]), "=&v"(r[2]), "=&v"(r[3])
    : "v"(p) : "memory");
}

// fast transcendentals: v_exp_f32-based, error << bf16 output rounding
__device__ __forceinline__ float fsigmoid(float x) {
  return 1.0f / (1.0f + __expf(-x));
}
__device__ __forceinline__ float ftanh(float x) {
  return 1.0f - 2.0f / (__expf(2.0f * x) + 1.0f);
}

// 16-byte-granular load of 8 elements as bf16 fragment (plain/cached path).
__device__ __forceinline__ short8 loadA8(const void* base, bool bf, size_t eidx) {
  if (bf) return *(const short8*)((const ushort*)base + eidx);
  const uint4* f = (const uint4*)((const float*)base + eidx);
  uint4 lo = f[0];
  uint4 hi = f[1];
  U8 r;
  r.u[0] = __builtin_amdgcn_perm(lo.y, lo.x, 0x07060302);
  r.u[1] = __builtin_amdgcn_perm(lo.w, lo.z, 0x07060302);
  r.u[2] = __builtin_amdgcn_perm(hi.y, hi.x, 0x07060302);
  r.u[3] = __builtin_amdgcn_perm(hi.w, hi.z, 0x07060302);
  return r.s;
}
__device__ __forceinline__ short8 loadW8(const void* base, bool bf, size_t eidx) {
  if (bf) return *(const short8*)((const ushort*)base + eidx);
  const float* f = (const float*)base + eidx;
  short8 r;
  #pragma unroll
  for (int i = 0; i < 8; i++) r[i] = (short)f2b(f[i]);
  return r;
}
__device__ __forceinline__ float loadS(const void* p, bool bf, size_t i) {
  return bf ? b2f(((const ushort*)p)[i]) : ((const float*)p)[i];
}

__device__ __forceinline__ bool detect_bf16(const unsigned* xw, int tid, int nthr, int* sh) {
  if (tid == 0) *sh = 0;
  __syncthreads();
  int c = 0;
  for (int i = tid; i < 4096; i += nthr) {
    int e = (int)((xw[i] >> 7) & 0xFF);
    c += (e >= 110 && e <= 140) ? 1 : 0;
  }
  atomicAdd(sh, c);
  __syncthreads();
  return *sh > 2048;
}

// flag line: flags[((grp*WPG + wgi)*4 + rep)*32], 128B apart
__device__ __forceinline__ unsigned* flagp(unsigned* flags, int grp, int wgi, int rep) {
  return flags + (((grp * WPG + wgi) * 4 + rep) * 32);
}

// ---------------------------------------------------------------------------
// Persistent pipelined GRU scan, GX2 merged into L1 (3 groups, 72 WGs).
// Groups: 0=GX1 (w_ih1 @ x[s]),
//         1=L1  (w_hh1 @ h1 AND w_ih2 @ h1 on the same staged tile
//                -> h1[s] and gx2[s']),
//         2=GH2 (w_hh2 @ h2 + combine -> y2[s] = h2 history)
// lag = {0,1,4}. At tick t:
//   GX1: gx1[t]                      (slot t&3)
//   L1 : stages h1[t-2]; computes gh1 -> h1[t-1] (slot (t-1)&3)
//        and gx2[t-2] = w_ih2 @ h1[t-2] (slot (t-2)&3)  [runs thru t=TLEN+1]
//   GH2: stages h2[t-5] (from y2); gx2[t-4] + gh2 -> h2[t-4] -> y2
// Flag value = ticks completed (posted t+1 after end-of-tick drain barrier).
// Waits (flag >= t + off):
//   GX1: F_L1 r2[wgi]  -2  (gx1 slot reuse; GX1 free-runs ~2 ahead)
//   L1 : F_GX1 r0[wgi]  0  (gx1[t-1] ready; pre-satisfied in steady state)
//        F_L1  r0[all]  0  (peers' h1[t-2])                <- critical
//        F_GH2 r1[wgi] -1  (gx2 slot reuse; GH2 consumed gx2[t-6] at t-2)
//   GH2: F_L1  r1[wgi] -1  (gx2[t-4] stored by L1 at its tick t-2)
//        F_GH2 r0[all]  0  (peers' h2[t-5] in y2)          <- critical
// gx2 slicing aligns: L1 WG wgi produces exactly the gate-columns GH2 WG wgi
// consumes, so the r1 edges are single-poller per line.
// ---------------------------------------------------------------------------
__global__ __launch_bounds__(NTHR, 1) void scan_kernel(
    const void* __restrict__ x,        // [16][1024][768]
    const void* __restrict__ w_ih,     // [2][2304][768]
    const void* __restrict__ w_hh,     // [2][2304][768]
    const void* __restrict__ b_ih,     // [2][2304]
    const void* __restrict__ b_hh,     // [2][2304]
    unsigned int* flags,               // [4][24][4][32] padded flags (zeroed)
    unsigned int* dflag,               // dtype flag out (for fc)
    ushort* h1buf,                     // [4][16][768] bf16
    float*  gxbuf1,                    // [4][24][16][96] f32 (per-WG slices)
    float*  gxbuf2,                    // [4][24][16][96] f32
    ushort* y2)                        // [16][1024][768] bf16 (= h2 history)
{
  const int wg   = blockIdx.x;
  const int grp  = wg / WPG;           // 0=GX1, 1=L1, 2=GH2
  const int wgi  = wg % WPG;           // 0..23 -> gate columns [wgi*32, wgi*32+32)
  const int tid  = threadIdx.x;
  const int wave = tid >> 6;           // 0..5
  const int lane = tid & 63;
  const int quad = lane >> 4;          // 0..3

  __shared__ ushort h_lds[BATCH * H];      // staged A tile (swizzled), 24 KB
  __shared__ float ghs[96 * 17];           // C tile A (gh or gx1)
  __shared__ float ghs2[96 * 17];          // C tile B (gx2, L1 only)
  __shared__ float hold[BATCH * SLICE];    // persistent fp32 h slice
  __shared__ float bih_s[96], bhh_s[96];
  __shared__ int   detsh;

  const bool isbf = detect_bf16((const unsigned*)x, tid, NTHR, &detsh);
  if (tid == 0) dflag[0] = isbf ? 1u : 0u;

  for (int i = tid; i < BATCH * SLICE; i += NTHR) hold[i] = 0.0f;

  if (grp >= 1) {
    size_t boff = (grp == 2) ? (size_t)G3 : 0;
    for (int gf = tid; gf < 96; gf += NTHR) {
      size_t gidx = boff + (size_t)(gf >> 5) * H + wgi * SLICE + (gf & 31);
      bih_s[gf] = loadS(b_ih, isbf, gidx);
      bhh_s[gf] = loadS(b_hh, isbf, gidx);
    }
  }

  // ---- per-lane poll pointer + threshold offset (wave 0 only) ----
  const unsigned* pollp = nullptr;
  int polloff = 0;
  if (wave == 0) {
    if (grp == 0) {
      if (lane == 0) { pollp = flagp(flags, 1, wgi, 2); polloff = -2; }
    } else if (grp == 1) {
      if      (lane == 0)  { pollp = flagp(flags, 0, wgi, 0);      polloff = 0;  }
      else if (lane <= 24) { pollp = flagp(flags, 1, lane - 1, 0); polloff = 0;  }
      else if (lane == 25) { pollp = flagp(flags, 2, wgi, 1);      polloff = -1; }
    } else {
      if      (lane == 0)  { pollp = flagp(flags, 1, wgi, 1);      polloff = -1; }
      else if (lane <= 24) { pollp = flagp(flags, 2, lane - 1, 0); polloff = 0;  }
    }
  }

  // ---- load this wave's B-fragments (16 gate rows x K=768) into registers --
  // grp0: w_ih layer1; grp1: w_hh layer1 (+ w_ih layer2 as bfrag2); grp2: w_hh layer2
  const void* WmatA = (grp == 0) ? w_ih : w_hh;
  const size_t woffA = (grp == 2) ? (size_t)G3 * H : 0;
  const int gate   = wave >> 1;                       // 0=r,1=z,2=n
  const int gfbase = gate * SLICE + (wave & 1) * 16;  // within-wg flat gate base
  const int nrow   = gate * H + wgi * SLICE + (wave & 1) * 16 + (lane & 15);
  const size_t wrow = (size_t)nrow * H + quad * 8;

  short8 bfrag[24];
  #pragma unroll
  for (int kk = 0; kk < 24; kk++)
    bfrag[kk] = loadW8(WmatA, isbf, woffA + wrow + kk * 32);

  short8 bfrag2[24];
  if (grp == 1) {
    #pragma unroll
    for (int kk = 0; kk < 24; kk++)
      bfrag2[kk] = loadW8(w_ih, isbf, (size_t)G3 * H + wrow + kk * 32);
  }

  // staging decomposition: thread -> (row b, 32-elem segment = 4 x 16B units)
  const int sb  = tid / 24;            // 0..15
  const int seg = tid % 24;            // 0..23
  const int sx  = sb & 7;              // staging swizzle key

  // combine decomposition: 256 threads, pairs of columns
  const int pb = tid >> 4;             // batch
  const int pj = (tid & 15) * 2;       // column pair
  const bool pact = (grp >= 1) && (tid < BATCH * SLICE / 2);

  const int lag = (grp == 1) ? 1 : ((grp == 2) ? 4 : 0);

  __syncthreads();

  for (int t = 0; t < TLEN + 4; t++) {
    const int tau = t - lag;
    const bool act_h = (tau >= 0) && (tau < TLEN);          // produce h / gx1
    const bool act_g = (grp == 1) && (t >= 2) && (t - 2 < TLEN);  // produce gx2
    const bool active = act_h || act_g;

    if (active) {
      // ---- dependency wait ----
      if (wave == 0) {
        for (;;) {
          int v = pollp ? (int)agent_ld32(pollp) : 0x7FFFFFFF;
          if (__ballot(v < t + polloff) == 0ull) break;
          __builtin_amdgcn_s_sleep(1);
        }
      }
      __syncthreads();

      // ---- early-issue combine-phase gx loads ----
      unsigned long long gr01 = 0, gz01 = 0, gn01 = 0;
      if (pact && act_h) {
        const float* gxr = ((grp == 1) ? gxbuf1 : gxbuf2)
            + ((size_t)((tau & 3) * WPG + wgi) * BATCH + pb) * 96;
        gr01 = agent_ld64(gxr + pj);
        gz01 = agent_ld64(gxr + 32 + pj);
        gn01 = agent_ld64(gxr + 64 + pj);
      }

      // ---- stage A tile (16 x 768) into LDS (XOR-swizzled units) ----
      if (grp == 0) {
        const size_t srcbase = ((size_t)sb * TLEN + tau) * H + seg * 32;
        #pragma unroll
        for (int i = 0; i < 4; i++) {
          short8 v = loadA8(x, isbf, srcbase + i * 8);
          *(short8*)&h_lds[sb * H + (((seg * 4 + i) ^ sx) * 8)] = v;
        }
      } else {
        const int hstep = (grp == 1) ? (t - 2) : (t - 5);
        u32x4 r4[4];
        if (hstep >= 0) {
          const ushort* src = (grp == 2)
              ? y2 + ((size_t)sb * TLEN + hstep) * H + seg * 32
              : h1buf + (size_t)(hstep & 3) * (BATCH * H) + (size_t)sb * H + seg * 32;
          ld64B_agent(src, r4);
        } else {
          r4[0] = (u32x4){0u, 0u, 0u, 0u};
          r4[1] = r4[0]; r4[2] = r4[0]; r4[3] = r4[0];
        }
        #pragma unroll
        for (int j = 0; j < 4; j++)
          *(u32x4*)&h_lds[sb * H + (((seg * 4 + j) ^ sx) * 8)] = r4[j];
      }
      __syncthreads();

      // ---- MFMA: A from LDS (swizzled read), B from registers ----
      const int ar  = lane & 15;
      const int arx = ar & 7;
      const ushort* abase = &h_lds[ar * H];
      f32x4 acc0 = {0.f, 0.f, 0.f, 0.f}, acc1 = {0.f, 0.f, 0.f, 0.f};
      f32x4 acc2 = {0.f, 0.f, 0.f, 0.f}, acc3 = {0.f, 0.f, 0.f, 0.f};
      if (grp == 1) {
        #pragma unroll
        for (int kk = 0; kk < 12; kk++) {
          short8 a0 = *(const short8*)&abase[((quad + 4 * kk) ^ arx) * 8];
          short8 a1 = *(const short8*)&abase[((quad + 4 * (kk + 12)) ^ arx) * 8];
          acc0 = __builtin_amdgcn_mfma_f32_16x16x32_bf16(a0, bfrag[kk],       acc0, 0, 0, 0);
          acc1 = __builtin_amdgcn_mfma_f32_16x16x32_bf16(a1, bfrag[kk + 12],  acc1, 0, 0, 0);
          acc2 = __builtin_amdgcn_mfma_f32_16x16x32_bf16(a0, bfrag2[kk],      acc2, 0, 0, 0);
          acc3 = __builtin_amdgcn_mfma_f32_16x16x32_bf16(a1, bfrag2[kk + 12], acc3, 0, 0, 0);
        }
      } else {
        #pragma unroll
        for (int kk = 0; kk < 12; kk++) {
          short8 a0 = *(const short8*)&abase[((quad + 4 * kk) ^ arx) * 8];
          short8 a1 = *(const short8*)&abase[((quad + 4 * (kk + 12)) ^ arx) * 8];
          acc0 = __builtin_amdgcn_mfma_f32_16x16x32_bf16(a0, bfrag[kk],      acc0, 0, 0, 0);
          acc1 = __builtin_amdgcn_mfma_f32_16x16x32_bf16(a1, bfrag[kk + 12], acc1, 0, 0, 0);
        }
      }
      f32x4 accA = acc0 + acc1;

      // ---- stage C tiles to LDS ----
      #pragma unroll
      for (int i = 0; i < 4; i++)
        ghs[(gfbase + ar) * 17 + quad * 4 + i] = accA[i];
      if (grp == 1) {
        f32x4 accB = acc2 + acc3;
        #pragma unroll
        for (int i = 0; i < 4; i++)
          ghs2[(gfbase + ar) * 17 + quad * 4 + i] = accB[i];
      }
      __syncthreads();

      if (grp == 0) {
        // pack gx1 slice [16][96] f32 -> coalesced 8B agent stores
        float* gxout = gxbuf1 + ((size_t)(tau & 3) * WPG + wgi) * BATCH * 96;
        const int m  = tid / 24;
        const int c4 = (tid % 24) * 4;
        union { unsigned long long q; float f[2]; } p0, p1;
        p0.f[0] = ghs[(c4 + 0) * 17 + m];
        p0.f[1] = ghs[(c4 + 1) * 17 + m];
        p1.f[0] = ghs[(c4 + 2) * 17 + m];
        p1.f[1] = ghs[(c4 + 3) * 17 + m];
        agent_st64(gxout + (size_t)m * 96 + c4,     p0.q);
        agent_st64(gxout + (size_t)m * 96 + c4 + 2, p1.q);
      } else {
        if (act_g) {
          // L1: pack gx2[t-2] slice from ghs2
          float* gxout = gxbuf2 + ((size_t)((t - 2) & 3) * WPG + wgi) * BATCH * 96;
          const int m  = tid / 24;
          const int c4 = (tid % 24) * 4;
          union { unsigned long long q; float f[2]; } p0, p1;
          p0.f[0] = ghs2[(c4 + 0) * 17 + m];
          p0.f[1] = ghs2[(c4 + 1) * 17 + m];
          p1.f[0] = ghs2[(c4 + 2) * 17 + m];
          p1.f[1] = ghs2[(c4 + 3) * 17 + m];
          agent_st64(gxout + (size_t)m * 96 + c4,     p0.q);
          agent_st64(gxout + (size_t)m * 96 + c4 + 2, p1.q);
        }
        if (act_h && pact) {
          union { unsigned long long q; float f[2]; } ur, uz, un;
          ur.q = gr01; uz.q = gz01; un.q = gn01;
          unsigned hpack = 0;
          #pragma unroll
          for (int s = 0; s < 2; s++) {
            const int j = pj + s;
            float rpre = ur.f[s] + bih_s[j]      + ghs[j * 17 + pb]        + bhh_s[j];
            float zpre = uz.f[s] + bih_s[32 + j] + ghs[(32 + j) * 17 + pb] + bhh_s[32 + j];
            float hn   = ghs[(64 + j) * 17 + pb] + bhh_s[64 + j];
            float r = fsigmoid(rpre);
            float z = fsigmoid(zpre);
            float n = ftanh(un.f[s] + bih_s[64 + j] + r * hn);
            float hnew = (1.0f - z) * n + z * hold[pb * SLICE + j];
            hold[pb * SLICE + j] = hnew;
            hpack |= ((unsigned)f2b(hnew)) << (16 * s);
          }
          if (grp == 1)
            agent_st32(h1buf + (size_t)(tau & 3) * (BATCH * H)
                             + (size_t)pb * H + wgi * SLICE + pj, hpack);
          else
            agent_st32(&y2[((size_t)pb * TLEN + tau) * H + wgi * SLICE + pj], hpack);
        }
      }
    }

    // ---- post completion flags (after vmcnt drain) ----
    __syncthreads();                       // drains vmcnt: comms stores visible
    if (tid < 3) agent_st32(flagp(flags, grp, wgi, tid), (unsigned)(t + 1));
  }
}

// ---------------------------------------------------------------------------
// Final FC (768->512) + bias + exact GELU.  M=16384, N=512, K=768.
// ---------------------------------------------------------------------------
__global__ __launch_bounds__(256) void fc_kernel(
    const ushort* __restrict__ y2,     // [16384][768] bf16 (internal)
    const void* __restrict__ w_fc,     // [512][768]
    const void* __restrict__ b_fc,     // [512]
    const unsigned* __restrict__ dflag,
    void* __restrict__ out)            // [16384][512]
{
  const bool isbf = dflag[0] != 0u;
  const int wave = threadIdx.x >> 6;
  const int lane = threadIdx.x & 63;
  const int col  = lane & 15;
  const int quad = lane >> 4;
  const int m0 = blockIdx.x * 64 + wave * 16;
  const int n0 = blockIdx.y * 64;

  const ushort* arow = y2 + (size_t)(m0 + col) * H + quad * 8;
  const size_t bbase = (size_t)(n0 + col) * H + quad * 8;

  f32x4 acc[4];
  #pragma unroll
  for (int nt = 0; nt < 4; nt++) acc[nt] = (f32x4){0.f, 0.f, 0.f, 0.f};

  for (int kk = 0; kk < 24; kk++) {
    short8 a = *(const short8*)(arow + kk * 32);
    #pragma unroll
    for (int nt = 0; nt < 4; nt++) {
      short8 b = loadA8(w_fc, isbf, bbase + (size_t)nt * 16 * H + kk * 32);
      acc[nt] = __builtin_amdgcn_mfma_f32_16x16x32_bf16(a, b, acc[nt], 0, 0, 0);
    }
  }

  #pragma unroll
  for (int nt = 0; nt < 4; nt++) {
    #pragma unroll
    for (int i = 0; i < 4; i++) {
      int m = m0 + quad * 4 + i;
      int n = n0 + nt * 16 + col;
      float v = acc[nt][i] + loadS(b_fc, isbf, n);
      float g = 0.5f * v * (1.0f + erff(v * 0.70710678118654752f));
      if (isbf) ((ushort*)out)[(size_t)m * DOUT + n] = f2b(g);
      else      ((float*)out)[(size_t)m * DOUT + n] = g;
    }
  }
}

extern "C" void kernel_launch(void* const* d_in, const int* in_sizes, int n_in,
                              void* d_out, int out_size, void* d_ws, size_t ws_size,
                              hipStream_t stream) {
  const void* x    = d_in[0];
  const void* w_ih = d_in[1];
  const void* w_hh = d_in[2];
  const void* b_ih = d_in[3];
  const void* b_hh = d_in[4];
  const void* w_fc = d_in[5];
  const void* b_fc = d_in[6];

  char* ws = (char*)d_ws;
  // layout: [0,49152) flags[4][24][4][32] | [49152,49156) dflag |
  //         [53248,151552) h1 (4-deep) | [151552,741376) gx1 (4-deep) |
  //         [741376,1331200) gx2 (4-deep) | [1331200,26497024) y2 (=h2 history)
  unsigned int* flags = (unsigned int*)(ws);
  unsigned int* dflag = (unsigned int*)(ws + 49152);
  ushort* h1buf  = (ushort*)(ws + 53248);
  float*  gxbuf1 = (float*)(ws + 151552);
  float*  gxbuf2 = (float*)(ws + 741376);
  ushort* y2     = (ushort*)(ws + 1331200);

  hipMemsetAsync(ws, 0, 49156, stream);  // flags + dflag only (data is flag-gated)
  scan_kernel<<<dim3(NWG), dim3(NTHR), 0, stream>>>(
      x, w_ih, w_hh, b_ih, b_hh, flags, dflag,
      h1buf, gxbuf1, gxbuf2, y2);
  fc_kernel<<<dim3(16384 / 64, DOUT / 64), dim3(256), 0, stream>>>(
      y2, w_fc, b_fc, dflag, (void*)d_out);
}

// Round 7
// 4134.429 us; speedup vs baseline: 1.2110x; 1.2110x over previous
//
#include <hip/hip_runtime.h>
#include <hip/hip_bf16.h>

#define H     768
#define G3    2304
#define BATCH 16
#define TLEN  1024
#define DOUT  512
#define GCOL  64      // gate columns per WG
#define WPG   12      // workgroups per group (768/64)
#define NWG   48      // 4 groups * 12
#define NTHR  768     // 12 waves

typedef __attribute__((ext_vector_type(8))) short short8;
typedef __attribute__((ext_vector_type(4))) float f32x4;
typedef __attribute__((ext_vector_type(4))) unsigned int u32x4;

union U8 { short8 s; unsigned u[4]; unsigned long long q[2]; };

__device__ __forceinline__ float b2f(ushort u) {
  union { unsigned int ui; float f; } v; v.ui = ((unsigned int)u) << 16; return v.f;
}
__device__ __forceinline__ ushort f2b(float f) {
  union { float f; unsigned int ui; } v; v.f = f;
  unsigned int u = v.ui;
  return (ushort)((u + 0x7fffu + ((u >> 16) & 1u)) >> 16);
}

// ---- agent-scope (cross-XCD coherent) relaxed accessors ----
__device__ __forceinline__ unsigned long long agent_ld64(const void* p) {
  return __hip_atomic_load((const unsigned long long*)p, __ATOMIC_RELAXED, __HIP_MEMORY_SCOPE_AGENT);
}
__device__ __forceinline__ unsigned agent_ld32(const void* p) {
  return __hip_atomic_load((const unsigned*)p, __ATOMIC_RELAXED, __HIP_MEMORY_SCOPE_AGENT);
}
__device__ __forceinline__ void agent_st32(void* p, unsigned v) {
  __hip_atomic_store((unsigned*)p, v, __ATOMIC_RELAXED, __HIP_MEMORY_SCOPE_AGENT);
}
__device__ __forceinline__ void agent_st64(void* p, unsigned long long v) {
  __hip_atomic_store((unsigned long long*)p, v, __ATOMIC_RELAXED, __HIP_MEMORY_SCOPE_AGENT);
}

// 32B coherent (agent-scope, cache-bypassing) load: 2 x dwordx4 with sc0 sc1.
__device__ __forceinline__ void ld32B_agent(const void* p, u32x4* r) {
  asm volatile(
    "global_load_dwordx4 %0, %2, off sc0 sc1\n\t"
    "global_load_dwordx4 %1, %2, off offset:16 sc0 sc1\n\t"
    "s_waitcnt vmcnt(0)"
    : "=&v"(r[0]), "=&v"(r[1])
    : "v"(p) : "memory");
}

// 16-byte-granular load of 8 elements as bf16 fragment (plain/cached path).
__device__ __forceinline__ short8 loadA8(const void* base, bool bf, size_t eidx) {
  if (bf) return *(const short8*)((const ushort*)base + eidx);
  const uint4* f = (const uint4*)((const float*)base + eidx);
  uint4 lo = f[0];
  uint4 hi = f[1];
  U8 r;
  r.u[0] = __builtin_amdgcn_perm(lo.y, lo.x, 0x07060302);
  r.u[1] = __builtin_amdgcn_perm(lo.w, lo.z, 0x07060302);
  r.u[2] = __builtin_amdgcn_perm(hi.y, hi.x, 0x07060302);
  r.u[3] = __builtin_amdgcn_perm(hi.w, hi.z, 0x07060302);
  return r.s;
}
__device__ __forceinline__ short8 loadW8(const void* base, bool bf, size_t eidx) {
  if (bf) return *(const short8*)((const ushort*)base + eidx);
  const float* f = (const float*)base + eidx;
  short8 r;
  #pragma unroll
  for (int i = 0; i < 8; i++) r[i] = (short)f2b(f[i]);
  return r;
}
__device__ __forceinline__ float loadS(const void* p, bool bf, size_t i) {
  return bf ? b2f(((const ushort*)p)[i]) : ((const float*)p)[i];
}

__device__ __forceinline__ bool detect_bf16(const unsigned* xw, int tid, int nthr, int* sh) {
  if (tid == 0) *sh = 0;
  __syncthreads();
  int c = 0;
  for (int i = tid; i < 4096; i += nthr) {
    int e = (int)((xw[i] >> 7) & 0xFF);
    c += (e >= 110 && e <= 140) ? 1 : 0;
  }
  atomicAdd(sh, c);
  __syncthreads();
  return *sh > 2048;
}

// flag line: flags[((grp*WPG + wgi)*4 + rep)*32], 128B apart
__device__ __forceinline__ unsigned* flagp(unsigned* flags, int grp, int wgi, int rep) {
  return flags + (((grp * WPG + wgi) * 4 + rep) * 32);
}

// ---------------------------------------------------------------------------
// Persistent pipelined GRU scan — round-4 protocol, regrouped to 12x768.
// Groups: 0=GX1 (w_ih1 @ x[s]),  1=L1 (w_hh1 @ h1 + combine -> h1[s]),
//         2=GX2 (w_ih2 @ h1[s]), 3=GH2 (w_hh2 @ h2 + combine -> y2[s]=h2[s])
// lag = {0,1,2,4}; tau = t - lag. gx1/gx2/h1 4-deep (slot = step&3);
// y2 holds the full h2 history. Flag value = ticks completed.
// Waits (flag >= t + off):
//   GX1: F_L1 r2[wgi]  -2   (gx1 slot reuse; GX1 free-runs ~2-3 ahead)
//   L1 : F_GX1 r0[wgi]  0   (gx1[t-1] ready; pre-satisfied steady-state)
//        F_L1  r0[all]  0   (peers' h1[t-2])               <- critical
//        F_GX2 r0[all] -2   (h1 slot reuse, 2 ticks slack)
//   GX2: F_L1  r1[all]  0   (h1[t-2] ready); F_GH2 r1[wgi] -1 (gx2 slot)
//   GH2: F_GX2 r1[wgi] -1   (gx2[t-4] ready); F_GH2 r0[all] 0 <- critical
// Each WG owns 64 gate-cols (192 rows, 12 waves). Per-flag-line pollers <=12.
// Data bulk-loaded once after flag (never polled).
// ---------------------------------------------------------------------------
__global__ __launch_bounds__(NTHR) void scan_kernel(
    const void* __restrict__ x,        // [16][1024][768]
    const void* __restrict__ w_ih,     // [2][2304][768]
    const void* __restrict__ w_hh,     // [2][2304][768]
    const void* __restrict__ b_ih,     // [2][2304]
    const void* __restrict__ b_hh,     // [2][2304]
    unsigned int* flags,               // [4][12][4][32] padded flags (zeroed)
    unsigned int* dflag,               // dtype flag out (for fc)
    ushort* h1buf,                     // [4][16][768] bf16
    float*  gxbuf1,                    // [4][12][16][192] f32 (per-WG slices)
    float*  gxbuf2,                    // [4][12][16][192] f32
    ushort* y2)                        // [16][1024][768] bf16 (= h2 history)
{
  const int wg   = blockIdx.x;
  const int grp  = wg / WPG;           // 0..3
  const int wgi  = wg % WPG;           // 0..11 -> gate columns [wgi*64, wgi*64+64)
  const int tid  = threadIdx.x;
  const int wave = tid >> 6;           // 0..11
  const int lane = tid & 63;
  const int quad = lane >> 4;          // 0..3
  const bool isL = (grp == 1 || grp == 3);

  __shared__ ushort h_lds[BATCH * H];      // staged A tile (swizzled), 24 KB
  __shared__ float ghs[192 * 17];          // MFMA C tile [gate-col][batch], 13 KB
  __shared__ float hold[BATCH * GCOL];     // persistent fp32 h slice, 4 KB
  __shared__ float bih_s[192], bhh_s[192];
  __shared__ int   detsh;

  const bool isbf = detect_bf16((const unsigned*)x, tid, NTHR, &detsh);
  if (tid == 0) dflag[0] = isbf ? 1u : 0u;

  for (int i = tid; i < BATCH * GCOL; i += NTHR) hold[i] = 0.0f;

  if (isL) {
    size_t boff = (grp == 3) ? (size_t)G3 : 0;
    for (int gf = tid; gf < 192; gf += NTHR) {
      size_t gidx = boff + (size_t)(gf >> 6) * H + wgi * GCOL + (gf & 63);
      bih_s[gf] = loadS(b_ih, isbf, gidx);
      bhh_s[gf] = loadS(b_hh, isbf, gidx);
    }
  }

  // ---- per-lane poll pointer + threshold offset (wave 0 only) ----
  const unsigned* pollp = nullptr;
  int polloff = 0;
  if (wave == 0) {
    if (grp == 0) {
      if (lane == 0) { pollp = flagp(flags, 1, wgi, 2); polloff = -2; }
    } else if (grp == 1) {
      if      (lane == 0)  { pollp = flagp(flags, 0, wgi, 0);       polloff = 0;  }
      else if (lane <= 12) { pollp = flagp(flags, 1, lane - 1, 0);  polloff = 0;  }
      else if (lane <= 24) { pollp = flagp(flags, 2, lane - 13, 0); polloff = -2; }
    } else if (grp == 2) {
      if      (lane < 12)  { pollp = flagp(flags, 1, lane, 1);      polloff = 0;  }
      else if (lane == 12) { pollp = flagp(flags, 3, wgi, 1);       polloff = -1; }
    } else {
      if      (lane == 0)  { pollp = flagp(flags, 2, wgi, 1);       polloff = -1; }
      else if (lane <= 12) { pollp = flagp(flags, 3, lane - 1, 0);  polloff = 0;  }
    }
  }

  // ---- load this wave's B-fragments (16 gate rows x K=768) into registers --
  const void* Wmat = (grp == 0 || grp == 2) ? w_ih : w_hh;
  const size_t woff = (grp >= 2) ? (size_t)G3 * H : 0;
  const int gate   = wave >> 2;                       // 0=r,1=z,2=n
  const int wchunk = wave & 3;                        // 16-col chunk in 64
  const int gfbase = gate * GCOL + wchunk * 16;       // within-wg flat gate base
  const int nrow   = gate * H + wgi * GCOL + wchunk * 16 + (lane & 15);
  const size_t wbase = woff + (size_t)nrow * H + quad * 8;

  short8 bfrag[24];
  #pragma unroll
  for (int kk = 0; kk < 24; kk++)
    bfrag[kk] = loadW8(Wmat, isbf, wbase + kk * 32);

  // staging decomposition: thread -> (row b, 16-elem segment = 2 x 16B units)
  const int sb  = tid / 48;            // 0..15
  const int seg = tid % 48;            // 0..47
  const int sx  = sb & 7;              // staging swizzle key

  // combine decomposition: 512 threads, pairs of columns
  const int pb = tid >> 5;             // batch (tid<512)
  const int pj = (tid & 31) * 2;       // column pair 0..62
  const bool pact = isL && (tid < BATCH * GCOL / 2);

  const int lag = (grp == 1) ? 1 : ((grp == 2) ? 2 : ((grp == 3) ? 4 : 0));

  __syncthreads();

  for (int t = 0; t < TLEN + 4; t++) {
    const int tau = t - lag;
    const bool active = (tau >= 0) && (tau < TLEN);

    if (active) {
      // ---- dependency wait ----
      if (wave == 0) {
        for (;;) {
          int v = pollp ? (int)agent_ld32(pollp) : 0x7FFFFFFF;
          if (__ballot(v < t + polloff) == 0ull) break;
          __builtin_amdgcn_s_sleep(1);
        }
      }
      __syncthreads();

      // ---- early-issue combine-phase gx loads (producer >=1 tick ahead) --
      unsigned long long gr01 = 0, gz01 = 0, gn01 = 0;
      if (pact) {
        const float* gxr = ((grp == 1) ? gxbuf1 : gxbuf2)
            + ((size_t)((tau & 3) * WPG + wgi) * BATCH + pb) * 192;
        gr01 = agent_ld64(gxr + pj);
        gz01 = agent_ld64(gxr + 64 + pj);
        gn01 = agent_ld64(gxr + 128 + pj);
      }

      // ---- stage A tile (16 x 768) into LDS (XOR-swizzled 16B units) ----
      if (grp == 0) {
        const size_t srcbase = ((size_t)sb * TLEN + tau) * H + seg * 16;
        short8 v0 = loadA8(x, isbf, srcbase);
        short8 v1 = loadA8(x, isbf, srcbase + 8);
        const int u0 = seg * 2, u1 = seg * 2 + 1;
        *(short8*)&h_lds[sb * H + (((u0 & ~7) | ((u0 & 7) ^ sx)) * 8)] = v0;
        *(short8*)&h_lds[sb * H + (((u1 & ~7) | ((u1 & 7) ^ sx)) * 8)] = v1;
      } else {
        const int hstep = (grp == 3) ? (t - 5) : (t - 2);
        u32x4 r4[2];
        if (hstep >= 0) {
          const ushort* src = (grp == 3)
              ? y2 + ((size_t)sb * TLEN + hstep) * H + seg * 16
              : h1buf + (size_t)(hstep & 3) * (BATCH * H) + (size_t)sb * H + seg * 16;
          ld32B_agent(src, r4);
        } else {
          r4[0] = (u32x4){0u, 0u, 0u, 0u};
          r4[1] = r4[0];
        }
        const int u0 = seg * 2, u1 = seg * 2 + 1;
        *(u32x4*)&h_lds[sb * H + (((u0 & ~7) | ((u0 & 7) ^ sx)) * 8)] = r4[0];
        *(u32x4*)&h_lds[sb * H + (((u1 & ~7) | ((u1 & 7) ^ sx)) * 8)] = r4[1];
      }
      __syncthreads();

      // ---- MFMA: A from LDS (swizzled read), B from registers ----
      const int ar  = lane & 15;
      const int arx = ar & 7;
      const ushort* abase = &h_lds[ar * H];
      f32x4 acc0 = {0.f, 0.f, 0.f, 0.f}, acc1 = {0.f, 0.f, 0.f, 0.f};
      #pragma unroll
      for (int kk = 0; kk < 12; kk++) {
        const int ua = quad + 4 * kk;
        const int ub = quad + 4 * (kk + 12);
        short8 a0 = *(const short8*)&abase[(((ua & ~7) | ((ua & 7) ^ arx)) * 8)];
        short8 a1 = *(const short8*)&abase[(((ub & ~7) | ((ub & 7) ^ arx)) * 8)];
        acc0 = __builtin_amdgcn_mfma_f32_16x16x32_bf16(a0, bfrag[kk],      acc0, 0, 0, 0);
        acc1 = __builtin_amdgcn_mfma_f32_16x16x32_bf16(a1, bfrag[kk + 12], acc1, 0, 0, 0);
      }
      f32x4 acc = acc0 + acc1;

      // ---- stage C tile to LDS ----
      #pragma unroll
      for (int i = 0; i < 4; i++)
        ghs[(gfbase + ar) * 17 + quad * 4 + i] = acc[i];
      __syncthreads();

      if (!isL) {
        // pack gx slice [16][192] f32 -> coalesced 8B agent stores
        float* gxout = ((grp == 0) ? gxbuf1 : gxbuf2)
            + ((size_t)(tau & 3) * WPG + wgi) * BATCH * 192;
        const int m  = tid / 48;
        const int c4 = (tid % 48) * 4;
        union { unsigned long long q; float f[2]; } p0, p1;
        p0.f[0] = ghs[(c4 + 0) * 17 + m];
        p0.f[1] = ghs[(c4 + 1) * 17 + m];
        p1.f[0] = ghs[(c4 + 2) * 17 + m];
        p1.f[1] = ghs[(c4 + 3) * 17 + m];
        agent_st64(gxout + (size_t)m * 192 + c4,     p0.q);
        agent_st64(gxout + (size_t)m * 192 + c4 + 2, p1.q);
      } else if (pact) {
        union { unsigned long long q; float f[2]; } ur, uz, un;
        ur.q = gr01; uz.q = gz01; un.q = gn01;
        unsigned hpack = 0;
        #pragma unroll
        for (int s = 0; s < 2; s++) {
          const int j = pj + s;
          float rpre = ur.f[s] + bih_s[j]       + ghs[j * 17 + pb]         + bhh_s[j];
          float zpre = uz.f[s] + bih_s[64 + j]  + ghs[(64 + j) * 17 + pb]  + bhh_s[64 + j];
          float hn   = ghs[(128 + j) * 17 + pb] + bhh_s[128 + j];
          float r = 1.0f / (1.0f + expf(-rpre));
          float z = 1.0f / (1.0f + expf(-zpre));
          float n = tanhf(un.f[s] + bih_s[128 + j] + r * hn);
          float hnew = (1.0f - z) * n + z * hold[pb * GCOL + j];
          hold[pb * GCOL + j] = hnew;
          hpack |= ((unsigned)f2b(hnew)) << (16 * s);
        }
        if (grp == 1)
          agent_st32(h1buf + (size_t)(tau & 3) * (BATCH * H)
                           + (size_t)pb * H + wgi * GCOL + pj, hpack);
        else
          agent_st32(&y2[((size_t)pb * TLEN + tau) * H + wgi * GCOL + pj], hpack);
      }
    }

    // ---- post completion flag (after vmcnt drain) ----
    __syncthreads();                       // drains vmcnt: comms stores visible
    if (tid < 3) agent_st32(flagp(flags, grp, wgi, tid), (unsigned)(t + 1));
  }
}

// ---------------------------------------------------------------------------
// Final FC (768->512) + bias + exact GELU.  M=16384, N=512, K=768.
// ---------------------------------------------------------------------------
__global__ __launch_bounds__(256) void fc_kernel(
    const ushort* __restrict__ y2,     // [16384][768] bf16 (internal)
    const void* __restrict__ w_fc,     // [512][768]
    const void* __restrict__ b_fc,     // [512]
    const unsigned* __restrict__ dflag,
    void* __restrict__ out)            // [16384][512]
{
  const bool isbf = dflag[0] != 0u;
  const int wave = threadIdx.x >> 6;
  const int lane = threadIdx.x & 63;
  const int col  = lane & 15;
  const int quad = lane >> 4;
  const int m0 = blockIdx.x * 64 + wave * 16;
  const int n0 = blockIdx.y * 64;

  const ushort* arow = y2 + (size_t)(m0 + col) * H + quad * 8;
  const size_t bbase = (size_t)(n0 + col) * H + quad * 8;

  f32x4 acc[4];
  #pragma unroll
  for (int nt = 0; nt < 4; nt++) acc[nt] = (f32x4){0.f, 0.f, 0.f, 0.f};

  for (int kk = 0; kk < 24; kk++) {
    short8 a = *(const short8*)(arow + kk * 32);
    #pragma unroll
    for (int nt = 0; nt < 4; nt++) {
      short8 b = loadA8(w_fc, isbf, bbase + (size_t)nt * 16 * H + kk * 32);
      acc[nt] = __builtin_amdgcn_mfma_f32_16x16x32_bf16(a, b, acc[nt], 0, 0, 0);
    }
  }

  #pragma unroll
  for (int nt = 0; nt < 4; nt++) {
    #pragma unroll
    for (int i = 0; i < 4; i++) {
      int m = m0 + quad * 4 + i;
      int n = n0 + nt * 16 + col;
      float v = acc[nt][i] + loadS(b_fc, isbf, n);
      float g = 0.5f * v * (1.0f + erff(v * 0.70710678118654752f));
      if (isbf) ((ushort*)out)[(size_t)m * DOUT + n] = f2b(g);
      else      ((float*)out)[(size_t)m * DOUT + n] = g;
    }
  }
}

extern "C" void kernel_launch(void* const* d_in, const int* in_sizes, int n_in,
                              void* d_out, int out_size, void* d_ws, size_t ws_size,
                              hipStream_t stream) {
  const void* x    = d_in[0];
  const void* w_ih = d_in[1];
  const void* w_hh = d_in[2];
  const void* b_ih = d_in[3];
  const void* b_hh = d_in[4];
  const void* w_fc = d_in[5];
  const void* b_fc = d_in[6];

  char* ws = (char*)d_ws;
  // layout: [0,24576) flags[4][12][4][32] | [24576,24580) dflag |
  //         [28672,126976) h1 (4-deep) | [126976,716800) gx1 (4-deep) |
  //         [716800,1306624) gx2 (4-deep) | [1306624,26472448) y2 (=h2)
  unsigned int* flags = (unsigned int*)(ws);
  unsigned int* dflag = (unsigned int*)(ws + 24576);
  ushort* h1buf  = (ushort*)(ws + 28672);
  float*  gxbuf1 = (float*)(ws + 126976);
  float*  gxbuf2 = (float*)(ws + 716800);
  ushort* y2     = (ushort*)(ws + 1306624);

  hipMemsetAsync(ws, 0, 24580, stream);  // flags + dflag only (data is flag-gated)
  scan_kernel<<<dim3(NWG), dim3(NTHR), 0, stream>>>(
      x, w_ih, w_hh, b_ih, b_hh, flags, dflag,
      h1buf, gxbuf1, gxbuf2, y2);
  fc_kernel<<<dim3(16384 / 64, DOUT / 64), dim3(256), 0, stream>>>(
      y2, w_fc, b_fc, dflag, (void*)d_out);
}

// Round 8
// 3552.839 us; speedup vs baseline: 1.4092x; 1.1637x over previous
//
#include <hip/hip_runtime.h>
#include <hip/hip_bf16.h>

#define H     768
#define G3    2304
#define BATCH 16
#define TLEN  1024
#define DOUT  512
#define SLICE 32
#define WPG   24      // workgroups per scan group (768/32)
#define NSCAN 96      // 4 scan groups * 24
#define NFC   64      // fused fc workgroups
#define NWG   160     // 96 scan + 64 fc
#define NTHR  384     // 6 waves

typedef __attribute__((ext_vector_type(8))) short short8;
typedef __attribute__((ext_vector_type(4))) float f32x4;
typedef __attribute__((ext_vector_type(4))) unsigned int u32x4;

union U8 { short8 s; unsigned u[4]; unsigned long long q[2]; };

__device__ __forceinline__ float b2f(ushort u) {
  union { unsigned int ui; float f; } v; v.ui = ((unsigned int)u) << 16; return v.f;
}
__device__ __forceinline__ ushort f2b(float f) {
  union { float f; unsigned int ui; } v; v.f = f;
  unsigned int u = v.ui;
  return (ushort)((u + 0x7fffu + ((u >> 16) & 1u)) >> 16);
}

// ---- agent-scope (cross-XCD coherent) relaxed accessors ----
__device__ __forceinline__ unsigned long long agent_ld64(const void* p) {
  return __hip_atomic_load((const unsigned long long*)p, __ATOMIC_RELAXED, __HIP_MEMORY_SCOPE_AGENT);
}
__device__ __forceinline__ unsigned agent_ld32(const void* p) {
  return __hip_atomic_load((const unsigned*)p, __ATOMIC_RELAXED, __HIP_MEMORY_SCOPE_AGENT);
}
__device__ __forceinline__ void agent_st32(void* p, unsigned v) {
  __hip_atomic_store((unsigned*)p, v, __ATOMIC_RELAXED, __HIP_MEMORY_SCOPE_AGENT);
}
__device__ __forceinline__ void agent_st64(void* p, unsigned long long v) {
  __hip_atomic_store((unsigned long long*)p, v, __ATOMIC_RELAXED, __HIP_MEMORY_SCOPE_AGENT);
}

// 64B coherent (agent-scope, cache-bypassing) load: 4 x dwordx4 with sc0 sc1.
__device__ __forceinline__ void ld64B_agent(const void* p, u32x4* r) {
  asm volatile(
    "global_load_dwordx4 %0, %4, off sc0 sc1\n\t"
    "global_load_dwordx4 %1, %4, off offset:16 sc0 sc1\n\t"
    "global_load_dwordx4 %2, %4, off offset:32 sc0 sc1\n\t"
    "global_load_dwordx4 %3, %4, off offset:48 sc0 sc1\n\t"
    "s_waitcnt vmcnt(0)"
    : "=&v"(r[0]), "=&v"(r[1]), "=&v"(r[2]), "=&v"(r[3])
    : "v"(p) : "memory");
}

// 16-byte-granular load of 8 elements as bf16 fragment (plain/cached path).
__device__ __forceinline__ short8 loadA8(const void* base, bool bf, size_t eidx) {
  if (bf) return *(const short8*)((const ushort*)base + eidx);
  const uint4* f = (const uint4*)((const float*)base + eidx);
  uint4 lo = f[0];
  uint4 hi = f[1];
  U8 r;
  r.u[0] = __builtin_amdgcn_perm(lo.y, lo.x, 0x07060302);
  r.u[1] = __builtin_amdgcn_perm(lo.w, lo.z, 0x07060302);
  r.u[2] = __builtin_amdgcn_perm(hi.y, hi.x, 0x07060302);
  r.u[3] = __builtin_amdgcn_perm(hi.w, hi.z, 0x07060302);
  return r.s;
}
__device__ __forceinline__ short8 loadW8(const void* base, bool bf, size_t eidx) {
  if (bf) return *(const short8*)((const ushort*)base + eidx);
  const float* f = (const float*)base + eidx;
  short8 r;
  #pragma unroll
  for (int i = 0; i < 8; i++) r[i] = (short)f2b(f[i]);
  return r;
}
__device__ __forceinline__ float loadS(const void* p, bool bf, size_t i) {
  return bf ? b2f(((const ushort*)p)[i]) : ((const float*)p)[i];
}

__device__ __forceinline__ bool detect_bf16(const unsigned* xw, int tid, int nthr, int* sh) {
  if (tid == 0) *sh = 0;
  __syncthreads();
  int c = 0;
  for (int i = tid; i < 4096; i += nthr) {
    int e = (int)((xw[i] >> 7) & 0xFF);
    c += (e >= 110 && e <= 140) ? 1 : 0;
  }
  atomicAdd(sh, c);
  __syncthreads();
  return *sh > 2048;
}

// flag line: flags[((grp*WPG + wgi)*4 + rep)*32], 128B apart
__device__ __forceinline__ unsigned* flagp(unsigned* flags, int grp, int wgi, int rep) {
  return flags + (((grp * WPG + wgi) * 4 + rep) * 32);
}

// ---------------------------------------------------------------------------
// Persistent pipelined GRU scan (round-4 protocol, verified) + fused FC group.
// Scan groups: 0=GX1 (w_ih1 @ x[s]),  1=L1 (w_hh1 @ h1 + combine -> h1[s]),
//              2=GX2 (w_ih2 @ h1[s]), 3=GH2 (w_hh2 @ h2 + combine -> y2[s])
// lag = {0,1,2,4}; tau = t - lag. gx1/gx2/h1 4-deep; y2 = full h2 history.
// Flag value = ticks completed (posted t+1 after end-of-tick drain barrier).
// Waits (flag >= t + off):
//   GX1: F_L1 r2[wgi]  -2 | L1: F_GX1 r0[wgi] 0, F_L1 r0[all] 0 (critical),
//   F_GX2 r0[all] -2 | GX2: F_L1 r1[all] 0, F_GH2 r1[wgi] -1 |
//   GH2: F_GX2 r1[wgi] -1, F_GH2 r0[all] 0 (critical).
// FC group (wg 96..159): 64 WGs; WG fcw owns t = fcw + 64*i (i=0..15).
// Per t: wait all 24 GH2 flags >= t+5 (y2[t] complete; replicas r2/r3,
// <=32 pollers/line), coherently stage y2[:,t,:] to LDS, MFMA vs w_fc,
// bias + exact GELU, store out. Purely additive: no new flags, no
// back-pressure (y2 append-only), scan protocol untouched.
// ---------------------------------------------------------------------------
__global__ __launch_bounds__(NTHR) void scan_kernel(
    const void* __restrict__ x,        // [16][1024][768]
    const void* __restrict__ w_ih,     // [2][2304][768]
    const void* __restrict__ w_hh,     // [2][2304][768]
    const void* __restrict__ b_ih,     // [2][2304]
    const void* __restrict__ b_hh,     // [2][2304]
    const void* __restrict__ w_fc,     // [512][768]
    const void* __restrict__ b_fc,     // [512]
    unsigned int* flags,               // [4][24][4][32] padded flags (zeroed)
    ushort* h1buf,                     // [4][16][768] bf16
    float*  gxbuf1,                    // [4][24][16][96] f32 (per-WG slices)
    float*  gxbuf2,                    // [4][24][16][96] f32
    ushort* y2,                        // [16][1024][768] bf16 (= h2 history)
    void* __restrict__ out)            // [16][1024][512] bf16 or f32
{
  const int wg   = blockIdx.x;
  const int tid  = threadIdx.x;
  const int wave = tid >> 6;           // 0..5
  const int lane = tid & 63;
  const int quad = lane >> 4;          // 0..3

  __shared__ ushort h_lds[BATCH * H];      // staged A tile (swizzled), 24 KB
  __shared__ float ghs[96 * 17];           // MFMA C tile [gate-col][batch]
  __shared__ float hold[BATCH * SLICE];    // persistent fp32 h slice
  __shared__ float bih_s[96], bhh_s[96];
  __shared__ int   detsh;

  const bool isbf = detect_bf16((const unsigned*)x, tid, NTHR, &detsh);

  // =========================== FC group ===================================
  if (wg >= NSCAN) {
    const int fcw = wg - NSCAN;        // 0..63
    const unsigned* fpoll = (wave == 0 && lane < WPG)
        ? flagp(flags, 3, lane, (fcw < 32) ? 2 : 3) : nullptr;
    const int sb  = tid / 24;          // 0..15 (batch row)
    const int seg = tid % 24;          // 0..23 (32-elem segment)
    const int sx  = sb & 7;
    const int ar  = lane & 15;
    const int arx = ar & 7;

    for (int i = 0; i < 16; i++) {
      const int t = fcw + 64 * i;
      // ---- wait: all GH2 WGs completed tick t+4 (=> y2[t] stored+acked) --
      if (wave == 0) {
        const int tgt = t + 5;
        for (;;) {
          int v = fpoll ? (int)agent_ld32(fpoll) : 0x7FFFFFFF;
          if (__ballot(v < tgt) == 0ull) break;
          __builtin_amdgcn_s_sleep(8);
        }
      }
      __syncthreads();

      // ---- stage y2[:, t, :] (16 x 768 bf16) into LDS, swizzled ---------
      {
        const ushort* src = y2 + ((size_t)sb * TLEN + t) * H + seg * 32;
        u32x4 r4[4];
        ld64B_agent(src, r4);
        #pragma unroll
        for (int j = 0; j < 4; j++)
          *(u32x4*)&h_lds[sb * H + (((seg * 4 + j) ^ sx) * 8)] = r4[j];
      }
      __syncthreads();

      // ---- MFMA: out[:, t, n0..n0+128) per wave (waves 0..3) ------------
      if (wave < 4) {
        const int n0 = wave * 128;
        const ushort* abase = &h_lds[ar * H];
        f32x4 acc[8];
        #pragma unroll
        for (int nt = 0; nt < 8; nt++) acc[nt] = (f32x4){0.f, 0.f, 0.f, 0.f};
        for (int kk = 0; kk < 12; kk++) {
          short8 a0 = *(const short8*)&abase[((quad + 4 * kk) ^ arx) * 8];
          short8 a1 = *(const short8*)&abase[((quad + 4 * (kk + 12)) ^ arx) * 8];
          #pragma unroll
          for (int nt = 0; nt < 8; nt++) {
            const size_t bb = (size_t)(n0 + nt * 16 + ar) * H + quad * 8;
            short8 b0 = loadA8(w_fc, isbf, bb + kk * 32);
            short8 b1 = loadA8(w_fc, isbf, bb + (kk + 12) * 32);
            acc[nt] = __builtin_amdgcn_mfma_f32_16x16x32_bf16(a0, b0, acc[nt], 0, 0, 0);
            acc[nt] = __builtin_amdgcn_mfma_f32_16x16x32_bf16(a1, b1, acc[nt], 0, 0, 0);
          }
        }
        #pragma unroll
        for (int nt = 0; nt < 8; nt++) {
          #pragma unroll
          for (int i2 = 0; i2 < 4; i2++) {
            const int b = quad * 4 + i2;
            const int n = n0 + nt * 16 + ar;
            float v = acc[nt][i2] + loadS(b_fc, isbf, n);
            float g = 0.5f * v * (1.0f + erff(v * 0.70710678118654752f));
            if (isbf) ((ushort*)out)[((size_t)b * TLEN + t) * DOUT + n] = f2b(g);
            else      ((float*)out)[((size_t)b * TLEN + t) * DOUT + n] = g;
          }
        }
      }
      __syncthreads();                 // LDS reuse guard before next t
    }
    return;
  }

  // =========================== scan groups (round-4, verified) ============
  const int grp  = wg / WPG;           // 0..3
  const int wgi  = wg % WPG;           // 0..23 -> gate columns [wgi*32, +32)
  const bool isL = (grp == 1 || grp == 3);

  for (int i = tid; i < BATCH * SLICE; i += NTHR) hold[i] = 0.0f;

  if (isL) {
    size_t boff = (grp == 3) ? (size_t)G3 : 0;
    for (int gf = tid; gf < 96; gf += NTHR) {
      size_t gidx = boff + (size_t)(gf >> 5) * H + wgi * SLICE + (gf & 31);
      bih_s[gf] = loadS(b_ih, isbf, gidx);
      bhh_s[gf] = loadS(b_hh, isbf, gidx);
    }
  }

  // ---- per-lane poll pointer + threshold offset (wave 0 only) ----
  const unsigned* pollp = nullptr;
  int polloff = 0;
  if (wave == 0) {
    if (grp == 0) {
      if (lane == 0) { pollp = flagp(flags, 1, wgi, 2); polloff = -2; }
    } else if (grp == 1) {
      if      (lane == 0)  { pollp = flagp(flags, 0, wgi, 0);       polloff = 0;  }
      else if (lane <= 24) { pollp = flagp(flags, 1, lane - 1, 0);  polloff = 0;  }
      else if (lane <= 48) { pollp = flagp(flags, 2, lane - 25, 0); polloff = -2; }
    } else if (grp == 2) {
      if      (lane < 24)  { pollp = flagp(flags, 1, lane, 1);      polloff = 0;  }
      else if (lane == 24) { pollp = flagp(flags, 3, wgi, 1);       polloff = -1; }
    } else {
      if      (lane == 0)  { pollp = flagp(flags, 2, wgi, 1);       polloff = -1; }
      else if (lane <= 24) { pollp = flagp(flags, 3, lane - 1, 0);  polloff = 0;  }
    }
  }

  // ---- load this wave's B-fragments (16 gate rows x K=768) into registers --
  const void* Wmat = (grp == 0 || grp == 2) ? w_ih : w_hh;
  const size_t woff = (grp >= 2) ? (size_t)G3 * H : 0;
  const int gate   = wave >> 1;                       // 0=r,1=z,2=n
  const int gfbase = gate * SLICE + (wave & 1) * 16;  // within-wg flat gate base
  const int nrow   = gate * H + wgi * SLICE + (wave & 1) * 16 + (lane & 15);
  const size_t wbase = woff + (size_t)nrow * H + quad * 8;

  short8 bfrag[24];
  #pragma unroll
  for (int kk = 0; kk < 24; kk++)
    bfrag[kk] = loadW8(Wmat, isbf, wbase + kk * 32);

  // staging decomposition: thread -> (row b, 32-elem segment = 4 x 16B units)
  const int sb  = tid / 24;            // 0..15
  const int seg = tid % 24;            // 0..23
  const int sx  = sb & 7;              // staging swizzle key

  // combine decomposition: 256 threads, pairs of columns
  const int pb = tid >> 4;             // batch
  const int pj = (tid & 15) * 2;       // column pair
  const bool pact = isL && (tid < BATCH * SLICE / 2);

  const int lag = (grp == 1) ? 1 : ((grp == 2) ? 2 : ((grp == 3) ? 4 : 0));

  __syncthreads();

  for (int t = 0; t < TLEN + 4; t++) {
    const int tau = t - lag;
    const bool active = (tau >= 0) && (tau < TLEN);

    if (active) {
      // ---- dependency wait ----
      if (wave == 0) {
        for (;;) {
          int v = pollp ? (int)agent_ld32(pollp) : 0x7FFFFFFF;
          if (__ballot(v < t + polloff) == 0ull) break;
          __builtin_amdgcn_s_sleep(1);
        }
      }
      __syncthreads();

      // ---- early-issue combine-phase gx loads (producer >=1 tick ahead) --
      unsigned long long gr01 = 0, gz01 = 0, gn01 = 0;
      if (pact) {
        const float* gxr = ((grp == 1) ? gxbuf1 : gxbuf2)
            + ((size_t)((tau & 3) * WPG + wgi) * BATCH + pb) * 96;
        gr01 = agent_ld64(gxr + pj);
        gz01 = agent_ld64(gxr + 32 + pj);
        gn01 = agent_ld64(gxr + 64 + pj);
      }

      // ---- stage A tile (16 x 768) into LDS (XOR-swizzled units) ----
      if (grp == 0) {
        const size_t srcbase = ((size_t)sb * TLEN + tau) * H + seg * 32;
        #pragma unroll
        for (int i = 0; i < 4; i++) {
          short8 v = loadA8(x, isbf, srcbase + i * 8);
          *(short8*)&h_lds[sb * H + (((seg * 4 + i) ^ sx) * 8)] = v;
        }
      } else {
        const int hstep = (grp == 3) ? (t - 5) : (t - 2);
        u32x4 r4[4];
        if (hstep >= 0) {
          const ushort* src = (grp == 3)
              ? y2 + ((size_t)sb * TLEN + hstep) * H + seg * 32
              : h1buf + (size_t)(hstep & 3) * (BATCH * H) + (size_t)sb * H + seg * 32;
          ld64B_agent(src, r4);
        } else {
          r4[0] = (u32x4){0u, 0u, 0u, 0u};
          r4[1] = r4[0]; r4[2] = r4[0]; r4[3] = r4[0];
        }
        #pragma unroll
        for (int j = 0; j < 4; j++)
          *(u32x4*)&h_lds[sb * H + (((seg * 4 + j) ^ sx) * 8)] = r4[j];
      }
      __syncthreads();

      // ---- MFMA: A from LDS (swizzled read), B from registers ----
      const int ar  = lane & 15;
      const int arx = ar & 7;
      const ushort* abase = &h_lds[ar * H];
      f32x4 acc0 = {0.f, 0.f, 0.f, 0.f}, acc1 = {0.f, 0.f, 0.f, 0.f};
      #pragma unroll
      for (int kk = 0; kk < 12; kk++) {
        short8 a0 = *(const short8*)&abase[((quad + 4 * kk) ^ arx) * 8];
        short8 a1 = *(const short8*)&abase[((quad + 4 * (kk + 12)) ^ arx) * 8];
        acc0 = __builtin_amdgcn_mfma_f32_16x16x32_bf16(a0, bfrag[kk],      acc0, 0, 0, 0);
        acc1 = __builtin_amdgcn_mfma_f32_16x16x32_bf16(a1, bfrag[kk + 12], acc1, 0, 0, 0);
      }
      f32x4 acc = acc0 + acc1;

      // ---- stage C tile to LDS ----
      #pragma unroll
      for (int i = 0; i < 4; i++)
        ghs[(gfbase + ar) * 17 + quad * 4 + i] = acc[i];
      __syncthreads();

      if (!isL) {
        // pack gx slice [16][96] f32 -> coalesced 8B agent stores
        float* gxout = ((grp == 0) ? gxbuf1 : gxbuf2)
            + ((size_t)(tau & 3) * WPG + wgi) * BATCH * 96;
        const int m  = tid / 24;
        const int c4 = (tid % 24) * 4;
        union { unsigned long long q; float f[2]; } p0, p1;
        p0.f[0] = ghs[(c4 + 0) * 17 + m];
        p0.f[1] = ghs[(c4 + 1) * 17 + m];
        p1.f[0] = ghs[(c4 + 2) * 17 + m];
        p1.f[1] = ghs[(c4 + 3) * 17 + m];
        agent_st64(gxout + (size_t)m * 96 + c4,     p0.q);
        agent_st64(gxout + (size_t)m * 96 + c4 + 2, p1.q);
      } else if (pact) {
        union { unsigned long long q; float f[2]; } ur, uz, un;
        ur.q = gr01; uz.q = gz01; un.q = gn01;
        unsigned hpack = 0;
        #pragma unroll
        for (int s = 0; s < 2; s++) {
          const int j = pj + s;
          float rpre = ur.f[s] + bih_s[j]      + ghs[j * 17 + pb]        + bhh_s[j];
          float zpre = uz.f[s] + bih_s[32 + j] + ghs[(32 + j) * 17 + pb] + bhh_s[32 + j];
          float hn   = ghs[(64 + j) * 17 + pb] + bhh_s[64 + j];
          float r = 1.0f / (1.0f + expf(-rpre));
          float z = 1.0f / (1.0f + expf(-zpre));
          float n = tanhf(un.f[s] + bih_s[64 + j] + r * hn);
          float hnew = (1.0f - z) * n + z * hold[pb * SLICE + j];
          hold[pb * SLICE + j] = hnew;
          hpack |= ((unsigned)f2b(hnew)) << (16 * s);
        }
        if (grp == 1)
          agent_st32(h1buf + (size_t)(tau & 3) * (BATCH * H)
                           + (size_t)pb * H + wgi * SLICE + pj, hpack);
        else
          agent_st32(&y2[((size_t)pb * TLEN + tau) * H + wgi * SLICE + pj], hpack);
      }
    }

    // ---- post completion flag (after vmcnt drain) ----
    __syncthreads();                       // drains vmcnt: comms stores visible
    if (tid < 4) agent_st32(flagp(flags, grp, wgi, tid), (unsigned)(t + 1));
  }
}

extern "C" void kernel_launch(void* const* d_in, const int* in_sizes, int n_in,
                              void* d_out, int out_size, void* d_ws, size_t ws_size,
                              hipStream_t stream) {
  const void* x    = d_in[0];
  const void* w_ih = d_in[1];
  const void* w_hh = d_in[2];
  const void* b_ih = d_in[3];
  const void* b_hh = d_in[4];
  const void* w_fc = d_in[5];
  const void* b_fc = d_in[6];

  char* ws = (char*)d_ws;
  // layout: [0,49152) flags[4][24][4][32] |
  //         [53248,151552) h1 (4-deep) | [151552,741376) gx1 (4-deep) |
  //         [741376,1331200) gx2 (4-deep) | [1331200,26497024) y2 (=h2 history)
  unsigned int* flags = (unsigned int*)(ws);
  ushort* h1buf  = (ushort*)(ws + 53248);
  float*  gxbuf1 = (float*)(ws + 151552);
  float*  gxbuf2 = (float*)(ws + 741376);
  ushort* y2     = (ushort*)(ws + 1331200);

  hipMemsetAsync(ws, 0, 49152, stream);  // flags only (data is flag-gated)
  scan_kernel<<<dim3(NWG), dim3(NTHR), 0, stream>>>(
      x, w_ih, w_hh, b_ih, b_hh, w_fc, b_fc, flags,
      h1buf, gxbuf1, gxbuf2, y2, d_out);
}